// Round 18
// baseline (38.206 us; speedup 1.0000x reference)
//
#include <hip/hip_runtime.h>

// SoftHistLoss: x,y [16,3,512,512] f32 -> scalar f32
// R18: WAVE-LEVEL PIPE SPLIT. R16 proved LDS-atomic and VALU serialize
// WITHIN a wave; R17 proved occupancy isn't the limiter. So: waves 0,2 run
// the LDS-atomic path (R10 inner, ~52cyc/group incl 2 quarter-rate trans),
// waves 1,3 run the register path (R15 inner: acc[10] cndmask chain, zero
// LDS ops in loop, plain ds_write flush to thread-owned columns). Different
// co-resident waves -> CU overlaps the two pipes (m114-style). Per CU:
// LDS ops halved to 768 (~13us), per-SIMD VALU ~31.5K cyc (~13us) -> ~16-20us
// partial if overlap works.
// Math identical to R10 (proven absmax 2.441e-4):
//   pk = BASE + (trunc(s*scale) << sel), BASE=(255<<18)+1
//   m = 0.5-|d-0.5|, s = sigma(-15m); d<0.5: qa=255-trunc(255s), qb=0;
//   d>=0.5: qa=255, qb=trunc(62s). Fields qa[31:18] qb[17:7] cnt[6:0],
//   per-column <= 64 px -> no overflow. hist_i = A[i]-B[i]+B[i-1]+C[i+1]-A[i+1].
// Lessons: no FP LDS atomics (R2); no dependent LDS reads in hot loop (R9);
// no fat fused epilogue (R11); compile-time acc indices (R15); pipes sum
// within a wave (R16); occupancy not the issue (R17).

static constexpr int PLANES   = 48;               // 16*3 per image
static constexpr int PLANE_PX = 512 * 512;
static constexpr int SPP      = 16;               // sub-blocks per plane
static constexpr int THREADS  = 256;
static constexpr int CHUNK    = PLANE_PX / SPP;   // 16384 px/block, 64 px/thread
static constexpr int NBLK     = 96 * SPP;         // 1536 = 6 blocks/CU, one round
static constexpr unsigned BASE = (255u << 18) + 1u;

__global__ __launch_bounds__(THREADS, 6) void soft_hist_partial(
    const float* __restrict__ xin, const float* __restrict__ yin,
    unsigned* __restrict__ G /* [96][30] u32: per plane {A,B,C} x 10 bins */)
{
  __shared__ unsigned hist[11 * THREADS];         // row 10 = pad (v==1.0, atomic path)
  __shared__ unsigned red[10 * 16 * 3];
  const int t = threadIdx.x;
  #pragma unroll
  for (int s = 0; s < 11; ++s) hist[s * THREADS + t] = 0u;
  __syncthreads();

  const int blk   = blockIdx.x;
  const int plane = blk >> 4;                     // 0..95 (0..47 = x, 48..95 = y)
  const int sub   = blk & 15;
  const float* src = (plane < PLANES ? xin + (size_t)plane * PLANE_PX
                                     : yin + (size_t)(plane - PLANES) * PLANE_PX)
                   + (size_t)sub * CHUNK;
  const float4* src4 = (const float4*)src;
  unsigned* mycol = hist + t;
  const bool regpath = ((t >> 6) & 1) != 0;       // wave-uniform flavor

  constexpr int ITERS = CHUNK / (THREADS * 4);    // 16

  if (!regpath) {
    // ---- LDS-atomic waves (0,2): R10 inner verbatim ----
    float4 c0 = src4[t];
    float4 c1 = src4[THREADS + t];
    #pragma unroll 4
    for (int it = 0; it < ITERS; ++it) {
      float4 cur = c0;
      c0 = c1;
      if (it + 2 < ITERS) c1 = src4[(it + 2) * THREADS + t];
      float vv[4] = {cur.x, cur.y, cur.z, cur.w};
      #pragma unroll
      for (int j = 0; j < 4; ++j) {
        float W  = vv[j] * 10.0f;
        unsigned k = (unsigned)W;                 // k=10 -> pad row
        float d  = W - floorf(W);
        float mp = d - 0.5f;
        bool lo  = mp < 0.0f;
        float ex = __expf(fmaf(-15.0f, fabsf(mp), 7.5f));
        float sg = __builtin_amdgcn_rcpf(1.0f + ex);
        float scale = lo ? -255.0f : 62.0f;
        int   qs = (int)(sg * scale);
        unsigned sel = lo ? 18u : 7u;
        unsigned pk  = ((unsigned)qs << sel) + BASE;
        atomicAdd(&mycol[k << 8], pk);            // ds_add_u32
      }
    }
  } else {
    // ---- register waves (1,3): R15 inner, zero LDS in loop ----
    unsigned acc[10];
    #pragma unroll
    for (int b = 0; b < 10; ++b) acc[b] = 0u;
    float4 c0 = src4[t];
    float4 c1 = src4[THREADS + t];
    #pragma unroll 4
    for (int it = 0; it < ITERS; ++it) {
      float4 cur = c0;
      c0 = c1;
      if (it + 2 < ITERS) c1 = src4[(it + 2) * THREADS + t];
      float vv[4] = {cur.x, cur.y, cur.z, cur.w};
      #pragma unroll
      for (int j = 0; j < 4; ++j) {
        float W  = vv[j] * 10.0f;
        unsigned k = (unsigned)W;
        k = k > 9u ? 9u : k;                      // clamp (v==1.0 can't occur in [0,1))
        float d  = W - floorf(W);
        float mp = d - 0.5f;
        bool lo  = mp < 0.0f;
        float ex = __expf(fmaf(-15.0f, fabsf(mp), 7.5f));
        float sg = __builtin_amdgcn_rcpf(1.0f + ex);
        float scale = lo ? -255.0f : 62.0f;
        int   qs = (int)(sg * scale);
        unsigned sel = lo ? 18u : 7u;
        unsigned pk  = ((unsigned)qs << sel) + BASE;
        #pragma unroll
        for (int b = 0; b < 10; ++b)              // compile-time indices -> VGPRs
          acc[b] += (k == (unsigned)b) ? pk : 0u;
      }
    }
    // flush: thread-owned columns, plain writes (no races)
    #pragma unroll
    for (int b = 0; b < 10; ++b) mycol[b << 8] = acc[b];
  }
  __syncthreads();

  // stage 1: 160 threads, each sums 16 columns of one bin (unpacked fields)
  if (t < 160) {
    const int bin = t >> 4, grp = t & 15;
    const uint4* hp = (const uint4*)(hist + (bin << 8) + (grp << 4));
    unsigned sa = 0, sb = 0, sc = 0;
    #pragma unroll
    for (int q = 0; q < 4; ++q) {
      uint4 u4 = hp[q];
      unsigned uu[4] = {u4.x, u4.y, u4.z, u4.w};
      #pragma unroll
      for (int e = 0; e < 4; ++e) {
        unsigned u = uu[e];
        sa += u >> 18; sb += (u >> 7) & 0x7FFu; sc += u & 0x7Fu;
      }
    }
    const int base = (bin * 16 + grp) * 3;
    red[base] = sa; red[base + 1] = sb; red[base + 2] = sc;
  }
  __syncthreads();

  // stage 2: 30 threads -> global integer atomics (deterministic)
  if (t < 30) {
    const int bin = t / 3, c = t - 3 * bin;
    unsigned s = 0;
    #pragma unroll
    for (int g = 0; g < 16; ++g) s += red[(bin * 16 + g) * 3 + c];
    atomicAdd(&G[plane * 30 + bin * 3 + c], s);
  }
}

__global__ __launch_bounds__(512) void soft_hist_loss(
    const unsigned* __restrict__ G, float* __restrict__ out)
{
  __shared__ float wred[8];
  const int t = threadIdx.x;
  float val = 0.0f;
  if (t < 480) {
    const int pc = t / 10;        // (batch,channel) 0..47
    const int i  = t - pc * 10;   // bin
    const unsigned* gx = G + pc * 30;
    const unsigned* gy = G + (pc + PLANES) * 30;
    // hist_i = A[i]/255 - B[i]/62 + B[i-1]/62 + C[i+1] - A[i+1]/255
    float hx = (float)gx[3 * i] * (1.0f / 255.0f)
             - (float)gx[3 * i + 1] * (1.0f / 62.0f)
             + (i > 0 ? (float)gx[3 * (i - 1) + 1] * (1.0f / 62.0f) : 0.0f)
             + (i < 9 ? (float)gx[3 * (i + 1) + 2]
                      - (float)gx[3 * (i + 1)] * (1.0f / 255.0f) : 0.0f);
    float hy = (float)gy[3 * i] * (1.0f / 255.0f)
             - (float)gy[3 * i + 1] * (1.0f / 62.0f)
             + (i > 0 ? (float)gy[3 * (i - 1) + 1] * (1.0f / 62.0f) : 0.0f)
             + (i < 9 ? (float)gy[3 * (i + 1) + 2]
                      - (float)gy[3 * (i + 1)] * (1.0f / 255.0f) : 0.0f);
    val = fabsf(hx - hy);
  }
  #pragma unroll
  for (int off = 32; off >= 1; off >>= 1) val += __shfl_xor(val, off, 64);
  if ((t & 63) == 0) wred[t >> 6] = val;
  __syncthreads();
  if (t == 0) {
    float s = 0.0f;
    #pragma unroll
    for (int w = 0; w < 8; ++w) s += wred[w];
    // loss = sum * (1/BINS) * (1/B) * 1e-4
    out[0] = s * 6.25e-7f;
  }
}

extern "C" void kernel_launch(void* const* d_in, const int* in_sizes, int n_in,
                              void* d_out, int out_size, void* d_ws, size_t ws_size,
                              hipStream_t stream) {
  const float* x = (const float*)d_in[0];
  const float* y = (const float*)d_in[1];
  unsigned* G = (unsigned*)d_ws;               // 96*30*4 = 11520 B
  hipMemsetAsync(d_ws, 0, 96 * 30 * sizeof(unsigned), stream);
  soft_hist_partial<<<NBLK, THREADS, 0, stream>>>(x, y, G);
  soft_hist_loss<<<1, 512, 0, stream>>>(G, (float*)d_out);
}